// Round 2
// 1389.958 us; speedup vs baseline: 1.1079x; 1.1079x over previous
//
#include <hip/hip_runtime.h>
#include <hip/hip_bf16.h>

#define B_TOT 65536

// Pure-VALU fp32 reference-mirror kernel. 32 rows per block, 256 threads.
// Bit-identical accumulation order to the 1552us baseline; adds:
//  - S5: 2-emb-dims-per-pass, rows in 2 halves of 16 (VGPR relief),
//        double-buffered Wp loads
//  - S2/S3/S4: software-pipelined (rotated) weight loads
//  - psum/dist LDS layout swizzle (n+r)&63 -> conflict-free S6
// LDS: A_ = xs[32][160] -> h2[32][256] -> psum[32][4][64] (swizzled)
//      Bb = h1[32][256] -> feat[32][128] | dist[32][64]@4096 (swizzled) | idx@6144
__global__ __launch_bounds__(256, 2) void udp_kernel(
    const float* __restrict__ obs, const float* __restrict__ act,
    const float* __restrict__ obs2, const float* __restrict__ rew,
    const float* __restrict__ W0, const float* __restrict__ b0,
    const float* __restrict__ W1, const float* __restrict__ b1,
    const float* __restrict__ W2, const float* __restrict__ b2,
    const float* __restrict__ Wp, const float* __restrict__ emb,
    const float* __restrict__ sigma, float* __restrict__ out) {
  __shared__ __align__(16) float A_[8192];
  __shared__ __align__(16) float Bb[8192];
  const int t = threadIdx.x;
  const int blockRow = blockIdx.x * 32;

  float* out0 = out;                        // chosen_embedding (B,32)
  float* out1 = out + (size_t)B_TOT * 32;   // chosen_dist (B,1)
  float* out2 = out + (size_t)B_TOT * 33;   // idx (B,1) as float
  float* out3 = out + (size_t)B_TOT * 34;   // chosen_mean (B,32)
  float* out4 = out + (size_t)B_TOT * 66;   // distance (B,64)

  // ---- S1: stage x = [obs | obs2-obs | act | rew] fp32 into A_ ----
  for (int i = t; i < 32 * 160; i += 256) {
    int r = i / 160, k = i - r * 160;
    int row = blockRow + r;
    float v;
    if (k < 64)        v = obs[row * 64 + k];
    else if (k < 128)  v = obs2[row * 64 + (k - 64)] - obs[row * 64 + (k - 64)];
    else if (k < 144)  v = act[row * 16 + (k - 128)];
    else if (k == 144) v = rew[row];
    else               v = 0.f;
    A_[i] = v;
  }
  __syncthreads();

  // ---- S2: layer 0 (145 -> 256). thread = neuron t; 32 rows in regs ----
  {
    float acc[32];
#pragma unroll
    for (int r = 0; r < 32; ++r) acc[r] = 0.f;
    const float bb = b0[t];
    const float wt = W0[144 * 256 + t];  // tail weight, load early
    float w0v = W0[0 * 256 + t], w1v = W0[1 * 256 + t];
    float w2v = W0[2 * 256 + t], w3v = W0[3 * 256 + t];
    for (int k4 = 0; k4 < 144; k4 += 4) {
      const int kn = (k4 + 4 < 144) ? (k4 + 4) : 0;  // wrap: last prefetch unused
      float n0 = W0[(kn + 0) * 256 + t];
      float n1 = W0[(kn + 1) * 256 + t];
      float n2 = W0[(kn + 2) * 256 + t];
      float n3 = W0[(kn + 3) * 256 + t];
#pragma unroll
      for (int r = 0; r < 32; ++r) {
        const float4 xv = *(const float4*)&A_[r * 160 + k4];  // LDS broadcast
        acc[r] = fmaf(xv.x, w0v, acc[r]);
        acc[r] = fmaf(xv.y, w1v, acc[r]);
        acc[r] = fmaf(xv.z, w2v, acc[r]);
        acc[r] = fmaf(xv.w, w3v, acc[r]);
      }
      w0v = n0; w1v = n1; w2v = n2; w3v = n3;
    }
#pragma unroll
    for (int r = 0; r < 32; ++r) acc[r] = fmaf(A_[r * 160 + 144], wt, acc[r]);
#pragma unroll
    for (int r = 0; r < 32; ++r) {
      float v = acc[r] + bb;
      v = v > 0.f ? v : 0.01f * v;
      Bb[r * 256 + t] = v;  // h1
    }
  }
  __syncthreads();

  // ---- S3: layer 1 (256 -> 256) ----
  {
    float acc[32];
#pragma unroll
    for (int r = 0; r < 32; ++r) acc[r] = 0.f;
    const float bb = b1[t];
    float w0v = W1[0 * 256 + t], w1v = W1[1 * 256 + t];
    float w2v = W1[2 * 256 + t], w3v = W1[3 * 256 + t];
    for (int k4 = 0; k4 < 256; k4 += 4) {
      const int kn = (k4 + 4) & 255;  // wraps to 0 on last iter (unused)
      float n0 = W1[(kn + 0) * 256 + t];
      float n1 = W1[(kn + 1) * 256 + t];
      float n2 = W1[(kn + 2) * 256 + t];
      float n3 = W1[(kn + 3) * 256 + t];
#pragma unroll
      for (int r = 0; r < 32; ++r) {
        const float4 hv = *(const float4*)&Bb[r * 256 + k4];  // broadcast
        acc[r] = fmaf(hv.x, w0v, acc[r]);
        acc[r] = fmaf(hv.y, w1v, acc[r]);
        acc[r] = fmaf(hv.z, w2v, acc[r]);
        acc[r] = fmaf(hv.w, w3v, acc[r]);
      }
      w0v = n0; w1v = n1; w2v = n2; w3v = n3;
    }
    // A_ (xs) fully consumed -> safe to overwrite
#pragma unroll
    for (int r = 0; r < 32; ++r) {
      float v = acc[r] + bb;
      v = v > 0.f ? v : 0.01f * v;
      A_[r * 256 + t] = v;  // h2
    }
  }
  __syncthreads();

  // ---- S4: layer 2 (256 -> 128). thread = (neuron t&127, row-half t>>7) ----
  {
    const int n = t & 127, half = t >> 7;  // half uniform per wave
    float acc[16];
#pragma unroll
    for (int r = 0; r < 16; ++r) acc[r] = 0.f;
    const float bb = b2[n];
    float w0v = W2[0 * 128 + n], w1v = W2[1 * 128 + n];
    float w2v = W2[2 * 128 + n], w3v = W2[3 * 128 + n];
    for (int k4 = 0; k4 < 256; k4 += 4) {
      const int kn = (k4 + 4) & 255;
      float n0 = W2[(kn + 0) * 128 + n];
      float n1 = W2[(kn + 1) * 128 + n];
      float n2 = W2[(kn + 2) * 128 + n];
      float n3 = W2[(kn + 3) * 128 + n];
#pragma unroll
      for (int r = 0; r < 16; ++r) {
        const float4 hv = *(const float4*)&A_[(half * 16 + r) * 256 + k4];
        acc[r] = fmaf(hv.x, w0v, acc[r]);
        acc[r] = fmaf(hv.y, w1v, acc[r]);
        acc[r] = fmaf(hv.z, w2v, acc[r]);
        acc[r] = fmaf(hv.w, w3v, acc[r]);
      }
      w0v = n0; w1v = n1; w2v = n2; w3v = n3;
    }
#pragma unroll
    for (int r = 0; r < 16; ++r) {
      float v = acc[r] + bb;
      v = v > 0.f ? v : 0.01f * v;
      Bb[(half * 16 + r) * 128 + n] = v;  // feat in Bb[0..4095]
    }
  }
  __syncthreads();

  // ---- S5: projection + diff^2 partials (numpy pairwise tree) ----
  // thread = (env n = t&63, partial p = t>>6 wave-uniform). numpy's 8
  // accumulators r_j (j = e mod 8, m ascending); this thread owns
  // j in {2p, 2p+1}. Per m-pass compute BOTH e = 2p+8m and e+1, rows
  // processed in 2 halves of 16 (cuts peak VGPR); each LDS feat read
  // feeds 8 FMAs; Wp float4 loads double-buffered one f4-step ahead.
  // Per-(thread,e,row) dot product keeps ascending-f4 FMA order and
  // per-accumulator m-ascending order -> bit-exact vs baseline.
  {
    const int n = t & 63, pp = t >> 6;
    float rj0[32], rj1[32];
#pragma unroll
    for (int r = 0; r < 32; ++r) { rj0[r] = 0.f; rj1[r] = 0.f; }
    const float* wb = Wp + (size_t)n * 32 * 128;
    const float* eb = emb + n * 32;
#pragma unroll 1
    for (int m = 0; m < 4; ++m) {
      const int e0 = 2 * pp + 8 * m;  // jj=0
      const int e1 = e0 + 1;          // jj=1
      const float* w0p = wb + e0 * 128;
      const float* w1p = wb + e1 * 128;
      const float em0 = eb[e0], em1 = eb[e1];
#pragma unroll 1
      for (int hh = 0; hh < 2; ++hh) {
        const int rbase = hh * 16;
        float acc0[16], acc1[16];
#pragma unroll
        for (int r = 0; r < 16; ++r) { acc0[r] = 0.f; acc1[r] = 0.f; }
        float4 wv0 = *(const float4*)(w0p);
        float4 wv1 = *(const float4*)(w1p);
        for (int f4 = 0; f4 < 128; f4 += 4) {
          const int fn = (f4 + 4) & 127;  // wrap: last prefetch harmless/in-bounds
          const float4 nv0 = *(const float4*)(w0p + fn);
          const float4 nv1 = *(const float4*)(w1p + fn);
#pragma unroll
          for (int r = 0; r < 16; ++r) {
            const float4 fv = *(const float4*)&Bb[(rbase + r) * 128 + f4];
            acc0[r] = fmaf(fv.x, wv0.x, acc0[r]);
            acc0[r] = fmaf(fv.y, wv0.y, acc0[r]);
            acc0[r] = fmaf(fv.z, wv0.z, acc0[r]);
            acc0[r] = fmaf(fv.w, wv0.w, acc0[r]);
            acc1[r] = fmaf(fv.x, wv1.x, acc1[r]);
            acc1[r] = fmaf(fv.y, wv1.y, acc1[r]);
            acc1[r] = fmaf(fv.z, wv1.z, acc1[r]);
            acc1[r] = fmaf(fv.w, wv1.w, acc1[r]);
          }
          wv0 = nv0; wv1 = nv1;
        }
#pragma unroll
        for (int r = 0; r < 16; ++r) {
          float d0 = acc0[r] - em0;
          rj0[rbase + r] = fmaf(d0, d0, rj0[rbase + r]);  // jj=0, this m
          float d1 = acc1[r] - em1;
          rj1[rbase + r] = fmaf(d1, d1, rj1[rbase + r]);  // jj=1, this m
        }
      }
    }
    // psum layout [r][pp][(n+r)&63]: write 2-way (free), S6 read conflict-free
#pragma unroll
    for (int r = 0; r < 32; ++r)
      A_[r * 256 + pp * 64 + ((n + r) & 63)] = rj0[r] + rj1[r];
  }
  __syncthreads();

  // ---- S6: distance + argmin per row (threads 0..31) ----
  if (t < 32) {
    const int r = t, row = blockRow + r;
    float best = 1e30f;
    int bi = 0;
    for (int n = 0; n < 64; ++n) {
      const int nr = (n + r) & 63;  // inverse of S5 swizzle
      const float p0 = A_[r * 256 + 0 * 64 + nr];
      const float p1 = A_[r * 256 + 1 * 64 + nr];
      const float p2 = A_[r * 256 + 2 * 64 + nr];
      const float p3 = A_[r * 256 + 3 * 64 + nr];
      float s = (p0 + p1) + (p2 + p3);  // numpy pairwise combine
      float mean = s / 32.0f;           // exact (pow2)
      float sg = sigma[n];
      float den = 2.0f * sg * sg;       // np: (2.0*s)*s
      float dist = expf((-mean) / den);
      Bb[4096 + r * 64 + nr] = dist;    // swizzled dist store (conflict-free)
      if (dist < best) { best = dist; bi = n; }  // np.argmin first-min
    }
    Bb[6144 + r] = (float)bi;
    out1[row] = best;
    out2[row] = (float)bi;
  }
  __syncthreads();

  // ---- S7a: distance matrix out (undo swizzle) ----
  for (int i = t; i < 32 * 64; i += 256) {
    int r = i >> 6, n = i & 63;
    out4[(size_t)(blockRow + r) * 64 + n] = Bb[4096 + r * 64 + ((n + r) & 63)];
  }
  // ---- S7b: chosen embedding (recompute f2e[idx]) + chosen mean ----
  for (int i = t; i < 32 * 32; i += 256) {
    int r = i >> 5, e = i & 31;
    int bi = (int)Bb[6144 + r];
    const float* wrow = Wp + (bi * 32 + e) * 128;
    float acc = 0.f;
    for (int f4 = 0; f4 < 128; f4 += 4) {
      const float4 wv = *(const float4*)(wrow + f4);
      const float4 fv = *(const float4*)&Bb[r * 128 + f4];
      acc = fmaf(fv.x, wv.x, acc);
      acc = fmaf(fv.y, wv.y, acc);
      acc = fmaf(fv.z, wv.z, acc);
      acc = fmaf(fv.w, wv.w, acc);
    }
    size_t row = (size_t)blockRow + r;
    out0[row * 32 + e] = acc;
    out3[row * 32 + e] = emb[bi * 32 + e];
  }
}

extern "C" void kernel_launch(void* const* d_in, const int* in_sizes, int n_in,
                              void* d_out, int out_size, void* d_ws, size_t ws_size,
                              hipStream_t stream) {
  const float* obs   = (const float*)d_in[0];
  const float* act   = (const float*)d_in[1];
  const float* obs2  = (const float*)d_in[2];
  const float* rew   = (const float*)d_in[3];
  const float* W0    = (const float*)d_in[4];
  const float* b0    = (const float*)d_in[5];
  const float* W1    = (const float*)d_in[6];
  const float* b1    = (const float*)d_in[7];
  const float* W2    = (const float*)d_in[8];
  const float* b2    = (const float*)d_in[9];
  const float* Wp    = (const float*)d_in[10];
  const float* e_emb = (const float*)d_in[11];
  const float* sigma = (const float*)d_in[12];

  udp_kernel<<<dim3(B_TOT / 32), dim3(256), 0, stream>>>(
      obs, act, obs2, rew, W0, b0, W1, b1, W2, b2, Wp, e_emb, sigma,
      (float*)d_out);
}